// Round 4
// baseline (365.785 us; speedup 1.0000x reference)
//
#include <hip/hip_runtime.h>

#define T_STEPS 100
#define CHUNKS  25              // 100 floats = 25 float4 per element
#define TPB     64              // one wave per block
#define ELEMS   64              // elements per tile (== TPB)
#define TILE_F4 (ELEMS * CHUNKS)  // 1600 float4 = 25.6 KB
#define GRID    2048            // 8192 tiles / 4 tiles per block

typedef const __attribute__((address_space(1))) unsigned int g_u32;
typedef __attribute__((address_space(3))) unsigned int l_u32;

// v5 = v1 (best measured: linear DMA, 86.6 us) + true LDS double buffer.
//
// Cross-round evidence: linear global reads dominate occupancy
//   (v1 linear/6 waves = 86.6 us > v3 80B-runs/16 waves ~99 > v4
//    16B-strided/14 waves = 129 ~ v2 single-buf persistent = 130).
// v1's remaining gap to the 67 us roofline is duty cycle: after the full
// vmcnt(0) drain, a wave holds ZERO memory in flight through ~3400 cyc of
// serial recurrence + epilogue -> CU oscillates all-load/all-compute.
//
// Fix: 2 x 25.6 KB LDS buffers (3 blocks/CU), 4 tiles per block:
//   prologue: DMA tile t -> buf0 ; vmcnt(0)
//   iter:     issue DMA tile t+GRID -> buf^1   (flies under compute)
//             compute buf (per-chunk ds_read b128, v1's 8-way-min pattern)
//             bitpack epilogue + 25 coalesced 1KB stores
//             s_waitcnt vmcnt(25)  <- retires ONLY the prefetch DMAs
//               (in-order vmcnt; queue = [DMA(25), stores(25)] -> wait-to-25
//                drains the DMAs, leaves stores in flight — the v2 mistake
//                of a serial ds_read/lgkm hoist before the issue is gone)
//             buf ^= 1
// Per-CU compute ~15.5 us << 67 us stream -> memory stays the limiter, now
// with ~100% load-in-flight duty.
//
// NUMERICS: float ops identical to bit-exact v1-v4 (contract off; op order
//   ((mem*TAU)+x)-w ; (BETA*w)+0.1*((A*m)+(B*s)); mem - spike*THRESH).
// Output path identical to v2/v3/v4 (absmax 0 verified): 100 spike bits in
// 4 u32, ds_bpermute transpose, exact 1.0f/0.0f expansion.
__global__ __launch_bounds__(TPB) void lif_kernel(const float* __restrict__ x,
                                                  float* __restrict__ out,
                                                  int nt) {
#pragma clang fp contract(off)
    __shared__ float4 tile[2][TILE_F4];   // 51.2 KB -> 3 blocks/CU

    const int lane = threadIdx.x;
    int t = blockIdx.x;
    if (t >= nt) return;

    // ---- prologue: DMA first tile -> buf0, drain once per block ----
    {
        const float4* __restrict__ xb = (const float4*)x + (size_t)t * TILE_F4;
#pragma unroll
        for (int k = 0; k < CHUNKS; ++k)
            __builtin_amdgcn_global_load_lds(
                (g_u32*)(xb + k * TPB + lane), (l_u32*)&tile[0][k * TPB], 16, 0, 0);
    }
    asm volatile("s_waitcnt vmcnt(0)" ::: "memory");
    __builtin_amdgcn_sched_barrier(0);

    int buf = 0;
    while (true) {
        const int nxt = t + GRID;
        const bool hn = nxt < nt;

        // ---- issue next tile's DMA into the other buffer (fire & forget) --
        if (hn) {
            const float4* __restrict__ xb = (const float4*)x + (size_t)nxt * TILE_F4;
#pragma unroll
            for (int k = 0; k < CHUNKS; ++k)
                __builtin_amdgcn_global_load_lds(
                    (g_u32*)(xb + k * TPB + lane),
                    (l_u32*)&tile[buf ^ 1][k * TPB], 16, 0, 0);
        }

        // ---- compute: own element's row from current buf (v1 pattern) -----
        unsigned b0 = 0, b1 = 0, b2 = 0, b3 = 0;
        float mem = 0.0f, wreg = 0.0f;
        const float4* tb = tile[buf];
#pragma unroll
        for (int c = 0; c < CHUNKS; ++c) {
            const float4 xv = tb[lane * CHUNKS + c];   // b128, stride 400B
            float xs[4] = {xv.x, xv.y, xv.z, xv.w};
#pragma unroll
            for (int j = 0; j < 4; ++j) {
                mem = (mem * 0.5f + xs[j]) - wreg;                 // ((mem*TAU)+x)-w
                const bool fire = (mem - 0.5f) > 0.0f;             // ZIF forward
                const float spike = fire ? 1.0f : 0.0f;
                wreg = 0.9f * wreg + 0.1f * (0.5f * mem + 0.5f * spike); // numpy order
                mem = mem - spike * 0.5f;                          // soft reset
                const int tt = c * 4 + j;                          // compile-time
                const unsigned bit = fire ? 1u : 0u;
                if (tt < 32)      b0 |= bit << tt;
                else if (tt < 64) b1 |= bit << (tt - 32);
                else if (tt < 96) b2 |= bit << (tt - 64);
                else              b3 |= bit << (tt - 96);
            }
        }

        // ---- epilogue: bpermute bits -> coalesced 1KB float4 stores -------
        float4* __restrict__ ob = (float4*)out + (size_t)t * TILE_F4;
#pragma unroll
        for (int k = 0; k < CHUNKS; ++k) {
            const int f  = k * TPB + lane;      // tile-local output f4 index
            const int el = f / 25;              // source element (lane)
            const int c  = f - el * 25;         // chunk within element
            const int a  = el << 2;             // bpermute byte address
            const unsigned w0 = (unsigned)__builtin_amdgcn_ds_bpermute(a, (int)b0);
            const unsigned w1 = (unsigned)__builtin_amdgcn_ds_bpermute(a, (int)b1);
            const unsigned w2 = (unsigned)__builtin_amdgcn_ds_bpermute(a, (int)b2);
            const unsigned w3 = (unsigned)__builtin_amdgcn_ds_bpermute(a, (int)b3);
            const unsigned word = (c < 16) ? ((c < 8) ? w0 : w1)
                                           : ((c < 24) ? w2 : w3);
            const int sh = (c & 7) * 4;         // bits 4c..4c+3 of element el
            float4 sv;
            sv.x = ((word >> (sh + 0)) & 1u) ? 1.0f : 0.0f;
            sv.y = ((word >> (sh + 1)) & 1u) ? 1.0f : 0.0f;
            sv.z = ((word >> (sh + 2)) & 1u) ? 1.0f : 0.0f;
            sv.w = ((word >> (sh + 3)) & 1u) ? 1.0f : 0.0f;
            ob[f] = sv;
        }

        if (!hn) break;
        // retire the prefetch DMAs only (stores stay in flight):
        // queue in issue order = [DMA_next(25), stores_cur(25)]
        asm volatile("s_waitcnt vmcnt(25)" ::: "memory");
        __builtin_amdgcn_sched_barrier(0);
        buf ^= 1;
        t = nxt;
    }
}

extern "C" void kernel_launch(void* const* d_in, const int* in_sizes, int n_in,
                              void* d_out, int out_size, void* d_ws, size_t ws_size,
                              hipStream_t stream) {
    const float* x = (const float*)d_in[0];
    float* out = (float*)d_out;
    int n_elem = in_sizes[0] / T_STEPS;   // 64*8192 = 524288
    int nt = n_elem / ELEMS;              // 8192 tiles
    int grid = nt < GRID ? nt : GRID;     // 2048 blocks, 4 tiles each

    lif_kernel<<<grid, TPB, 0, stream>>>(x, out, nt);
}

// Round 5
// 346.641 us; speedup vs baseline: 1.0552x; 1.0552x over previous
//
#include <hip/hip_runtime.h>

#define T_STEPS 100
#define CHUNKS  25     // 100 floats = 25 float4 per element
#define TPB     64     // one wave per block (v1 skeleton)
#define ELEMS   64     // elements per tile (== TPB)
#define SCH     21     // staged chunks in LDS (stride 21 f4 -> minimal bank aliasing)
#define DCH     4      // direct-to-VGPR chunks (21..24): 64 B contiguous per lane
#define TILE_F4 (ELEMS * CHUNKS)   // 1600 f4
#define SLDS    (ELEMS * SCH)      // 1344 f4 = 21504 B -> 7 blocks/CU (150.5/160 KB)

typedef const __attribute__((address_space(1))) unsigned int g_u32;
typedef __attribute__((address_space(3))) unsigned int l_u32;

// v6 = v1 skeleton (single-shot 1-wave blocks, linear DMA, one drain — the
// only structure that measured fast: 86.6 us) + 7-blocks/CU via split staging.
//
// Cross-round law (v1..v5): per-CU independent block-streams dominate
// everything (6 streams/linear = 86.6 > 16-wave strided = 99 > 14-wave
// 16B-stride = 129 ~ persistent double-buf = 130 ~ persistent single-buf=133).
// FETCH ~ half the input => reads are ~50% L3-served => floor is
// write-dominated; more concurrent streams is how L3-hit reads get exploited.
//
//  - LDS stages chunks 0..20 only: 21504 B/block -> 7 blocks/CU (+17% vs v1).
//    Chunks 21..24 (64 B/elem, per-lane contiguous) load directly to VGPRs,
//    issued FIRST and consumed LAST -> ~3000 cyc of latency hiding; their
//    lines are mostly L2/L3-resident.
//  - LDS layout [e][c<21], stride 21 f4: bank offset 84e%32=20e%32 covers all
//    32 banks in 8 lanes -> minimal 8 dwords/bank on ds_read_b128 (same as
//    v1's stride-25; a stride-20 layout would be a 32-way conflict).
//  - DMA dest stays linear (slot s = k*64+lane); global src is pre-skewed:
//    slot s holds (e=s/21, c=s%21) -> src f4 = 25e+c = s + 4*(s/21)
//    (m173 pattern: per-lane src, wave-uniform dest). Runs of 336 B.
//  - output: verified bitpack path (100 spike bits in 4 u32, exact) +
//    ds_bpermute transpose -> 25 coalesced 1 KB stores. No out-LDS, no
//    second barrier.
//
// NUMERICS: float ops identical to bit-exact v1-v5 (contract off; op order
//   ((mem*TAU)+x)-w ; (BETA*w)+0.1*((A*m)+(B*s)); mem - spike*THRESH).
__global__ __launch_bounds__(TPB) void lif_kernel(const float* __restrict__ x,
                                                  float* __restrict__ out) {
#pragma clang fp contract(off)
    __shared__ float4 lds[SLDS];   // 21504 B

    const int lane = threadIdx.x;
    const float4* __restrict__ xb = (const float4*)x + (size_t)blockIdx.x * TILE_F4;

    // ---- direct loads first (oldest in vm queue; consumed at the end) ----
    float4 dreg[DCH];
#pragma unroll
    for (int i = 0; i < DCH; ++i)
        dreg[i] = xb[lane * CHUNKS + SCH + i];   // own row, chunks 21..24

    // ---- staged DMAs: linear LDS dest, pre-skewed per-lane global src ----
#pragma unroll
    for (int k = 0; k < SCH; ++k) {
        const int s = k * 64 + lane;     // LDS f4 slot
        const int e = s / 21;            // element  (magic-mul)
        __builtin_amdgcn_global_load_lds(
            (g_u32*)(xb + s + 4 * e),    // src f4 = 25e + (s-21e) = s + 4e
            (l_u32*)&lds[k * 64], 16, 0, 0);
    }
    asm volatile("s_waitcnt vmcnt(0)" ::: "memory");   // single drain (v1 style)
    __builtin_amdgcn_sched_barrier(0);

    // ---- recurrence: 21 chunks from LDS, 4 from registers; bitpack spikes --
    unsigned b0 = 0, b1 = 0, b2 = 0, b3 = 0;
    float mem = 0.0f, wreg = 0.0f;

#define STEP4(XV, C)                                                        \
    do {                                                                    \
        float xs[4] = {(XV).x, (XV).y, (XV).z, (XV).w};                     \
        _Pragma("unroll")                                                   \
        for (int j = 0; j < 4; ++j) {                                       \
            mem = (mem * 0.5f + xs[j]) - wreg;     /* ((mem*TAU)+x)-w */    \
            const bool fire = (mem - 0.5f) > 0.0f; /* ZIF forward */        \
            const float spike = fire ? 1.0f : 0.0f;                         \
            wreg = 0.9f * wreg + 0.1f * (0.5f * mem + 0.5f * spike);        \
            mem = mem - spike * 0.5f;              /* soft reset */         \
            const int t = (C) * 4 + j;             /* compile-time */       \
            const unsigned bit = fire ? 1u : 0u;                            \
            if (t < 32)      b0 |= bit << t;                                \
            else if (t < 64) b1 |= bit << (t - 32);                         \
            else if (t < 96) b2 |= bit << (t - 64);                         \
            else             b3 |= bit << (t - 96);                         \
        }                                                                   \
    } while (0)

#pragma unroll
    for (int c = 0; c < SCH; ++c) {
        const float4 xv = lds[lane * SCH + c];   // b128, stride 336 B: min conflicts
        STEP4(xv, c);
    }
#pragma unroll
    for (int i = 0; i < DCH; ++i)
        STEP4(dreg[i], SCH + i);
#undef STEP4

    // ---- epilogue: bpermute elem bits -> coalesced 1 KB float4 stores ----
    float4* __restrict__ ob = (float4*)out + (size_t)blockIdx.x * TILE_F4;
#pragma unroll
    for (int k = 0; k < CHUNKS; ++k) {
        const int f  = k * TPB + lane;      // tile-local output f4 index
        const int el = f / 25;              // source element (lane)
        const int c  = f - el * 25;         // chunk within element
        const int a  = el << 2;             // bpermute byte address
        const unsigned w0 = (unsigned)__builtin_amdgcn_ds_bpermute(a, (int)b0);
        const unsigned w1 = (unsigned)__builtin_amdgcn_ds_bpermute(a, (int)b1);
        const unsigned w2 = (unsigned)__builtin_amdgcn_ds_bpermute(a, (int)b2);
        const unsigned w3 = (unsigned)__builtin_amdgcn_ds_bpermute(a, (int)b3);
        const unsigned word = (c < 16) ? ((c < 8) ? w0 : w1)
                                       : ((c < 24) ? w2 : w3);
        const int sh = (c & 7) * 4;         // bits 4c..4c+3 of element el
        float4 sv;
        sv.x = ((word >> (sh + 0)) & 1u) ? 1.0f : 0.0f;
        sv.y = ((word >> (sh + 1)) & 1u) ? 1.0f : 0.0f;
        sv.z = ((word >> (sh + 2)) & 1u) ? 1.0f : 0.0f;
        sv.w = ((word >> (sh + 3)) & 1u) ? 1.0f : 0.0f;
        ob[f] = sv;
    }
}

extern "C" void kernel_launch(void* const* d_in, const int* in_sizes, int n_in,
                              void* d_out, int out_size, void* d_ws, size_t ws_size,
                              hipStream_t stream) {
    const float* x = (const float*)d_in[0];
    float* out = (float*)d_out;
    int n_elem = in_sizes[0] / T_STEPS;   // 64*8192 = 524288
    int grid = n_elem / ELEMS;            // 8192 single-shot blocks

    lif_kernel<<<grid, TPB, 0, stream>>>(x, out);
}

// Round 6
// 345.216 us; speedup vs baseline: 1.0596x; 1.0041x over previous
//
#include <hip/hip_runtime.h>

#define T_STEPS 100
#define CHUNKS  25              // 100 floats = 25 float4 per element
#define TPB     64              // one wave per block (v1 skeleton, unchanged)
#define ELEMS   32              // elements per tile: HALF of v1 (the one variable)
#define TILE_F4 (ELEMS * CHUNKS)   // 800 float4 = 12.8 KB payload
#define NDMA    13              // ceil(800/64): 12 full DMAs + 1 padded
#define LDS_F4  (NDMA * 64)     // 832 f4 = 13312 B (slots 800..831 = pad)
// 13312 B/block -> 12 blocks/CU (159.7/160 KB): 2x v1's 6 streams/CU.

typedef const __attribute__((address_space(1))) unsigned int g_u32;
typedef __attribute__((address_space(3))) unsigned int l_u32;

// v7 = v1 verbatim with ONE variable changed: tile 64 -> 32 elements.
//
// Cross-round evidence: 346-class kernels (v1, v6) = single-shot blocks +
// linear DMA + one drain; 360-class (v2-v5) = persistence or strided reads.
// v6 bundled 3 changes (skewed DMA, strided direct loads, bitpack epilogue)
// with its occupancy bump and regressed per-dispatch; the stream-count lever
// was never tested in isolation. This tests it cleanly:
//  - DMA fully linear in src AND dest (the proven pattern). The 13th DMA
//    clamps src with (lane&31): lanes 32-63 re-read valid bytes and write
//    duplicate junk into pad slots 800..831 -- no predication, no skew.
//  - one vmcnt(0) drain; compute = v1's float recurrence, lanes 0-31 own
//    one element each (lanes 32-63 idle: VALU ~20% busy, not the limit);
//    in-place LDS spike write; LDS round-trip stage-out; coalesced stores.
//  - NO bitpack, NO bpermute, NO division (f4-linear round trip only).
//
// NUMERICS: bit-identical to v1 (absmax 0 verified): fp contract off;
//   ((mem*TAU)+x)-w ; (0.9*w)+0.1*((0.5*m)+(0.5*s)) ; mem - spike*0.5.
__global__ __launch_bounds__(TPB) void lif_kernel(const float* __restrict__ x,
                                                  float* __restrict__ out) {
#pragma clang fp contract(off)
    __shared__ float4 tile[LDS_F4];   // 13312 B

    const int lane = threadIdx.x;
    const size_t t4 = (size_t)blockIdx.x * TILE_F4;
    const float4* __restrict__ xb = (const float4*)x + t4;
    float4* __restrict__ ob = (float4*)out + t4;

    // ---- stage in: linear async DMA, 12 x 1KB + 1 padded ----
#pragma unroll
    for (int k = 0; k < NDMA - 1; ++k)
        __builtin_amdgcn_global_load_lds(
            (g_u32*)(xb + k * 64 + lane),       // per-lane linear global src
            (l_u32*)&tile[k * 64], 16, 0, 0);   // wave-uniform LDS base
    __builtin_amdgcn_global_load_lds(
        (g_u32*)(xb + 768 + (lane & 31)),       // clamped: lanes 32-63 dup
        (l_u32*)&tile[768], 16, 0, 0);          // dups land in pad 800..831
    __syncthreads();  // 1-wave block: compiles to the vmcnt/lgkm drain only

    // ---- compute: lane = element (lanes 0-31), v1 recurrence verbatim ----
    if (lane < ELEMS) {
        float mem = 0.0f;
        float w = 0.0f;
#pragma unroll
        for (int c = 0; c < CHUNKS; ++c) {
            float4 xv4 = tile[lane * CHUNKS + c];
            float xv[4] = {xv4.x, xv4.y, xv4.z, xv4.w};
            float sv[4];
#pragma unroll
            for (int j = 0; j < 4; ++j) {
                mem = (mem * 0.5f + xv[j]) - w;                    // ((mem*TAU)+x)-w
                float spike = (mem - 0.5f) > 0.0f ? 1.0f : 0.0f;   // ZIF forward
                w = 0.9f * w + 0.1f * (0.5f * mem + 0.5f * spike); // numpy order
                mem = mem - spike * 0.5f;                          // soft reset
                sv[j] = spike;
            }
            float4 s4;
            s4.x = sv[0]; s4.y = sv[1]; s4.z = sv[2]; s4.w = sv[3];
            tile[lane * CHUNKS + c] = s4;
        }
    }
    __syncthreads();  // drain ds_writes before cross-lane stage-out reads

    // ---- stage out: stride-1 LDS reads -> coalesced float4 stores ----
#pragma unroll
    for (int k = 0; k < NDMA - 1; ++k)
        ob[k * 64 + lane] = tile[k * 64 + lane];
    if (lane < 32)
        ob[768 + lane] = tile[768 + lane];      // payload tail (pad not stored)
}

extern "C" void kernel_launch(void* const* d_in, const int* in_sizes, int n_in,
                              void* d_out, int out_size, void* d_ws, size_t ws_size,
                              hipStream_t stream) {
    const float* x = (const float*)d_in[0];
    float* out = (float*)d_out;
    int n_elem = in_sizes[0] / T_STEPS;   // 64*8192 = 524288
    int grid = n_elem / ELEMS;            // 16384 single-shot blocks, exact

    lif_kernel<<<grid, TPB, 0, stream>>>(x, out);
}